// Round 12
// baseline (273.808 us; speedup 1.0000x reference)
//
#include <hip/hip_runtime.h>
#include <math.h>

// Sparsemax along axis 0 of z = -exp(a)*x, x: (4096, 8192) f32 row-major.
//
// R13: 2 dispatches. R12 post-mortem: removing a full 128MiB re-read pass
// saved only ~6us, and R5/R9/R12 all sit at ~100us non-fill budget despite
// totally different pipelines => per-dispatch fixed cost (~10us launch+drain)
// now rivals the work. So: fuse memset(out) into k_pmax as a COARSE second
// phase (block reads its 512KB x-slab, then zeroes its 512KB out-slab with
// plain float4 stores). Not R10's failure mode: R10 interleaved read/nt-write
// per line; here bursts are 512KB-pure and m13's 6.29TB/s float4-copy shows
// coarse mixed R+W streams run at full rate. Plain stores, not nt (nt is the
// common suspect in R7's hidden slow k3 and R10's +25us).
//
//   K1 k_pmax_zero: 256 blocks x 1024 thr; block = 16-row slab.
//       (a) sequential read of slab -> per-thread col-min over 8 owned cols
//           -> pminx[slab][col] (8 MiB, coalesced);
//       (b) zero the slab's 512KB region of out (contiguous float4 stores).
//   K2 k_solve: one wave per column (R12-proven).
//       (1) 256 slabmins -> butterfly -> colmin; thr = colmin + (1+eps)/|s|
//           in x-units (z > colmax_z-1 <=> x < thr, s<0; eps keeps the
//           candidate set a strict SUPERSET of the support under rounding).
//       (2) ballot-walk slabs with slabmin < thr (~2-3/col); lanes 0..15
//           gather the 16 elements, ballot-prefix compact into LDS.
//       (3) exact Michelot on <=64 candidates, scatter ~5 nonzeros over the
//           zeroed out. K>64 -> exact full-column fallback (correctness
//           never depends on statistics).
//
// ws: [0, 8M) pminx f32[256][8192].

constexpr int ROWS  = 4096;
constexpr int COLS  = 8192;
constexpr int SLAB  = 16;            // rows per slab
constexpr int NSLAB = ROWS / SLAB;   // 256
constexpr int CAPW  = 64;            // candidate capacity per column (1/lane)

// ---------- K1: sequential col-min slab partials + fused zero of out ----------
__global__ __launch_bounds__(1024)
void k_pmax_zero(const float* __restrict__ x, float* __restrict__ pminx,
                 float* __restrict__ out)
{
    const int t = threadIdx.x;
    const int b = blockIdx.x;
    const long row0 = (long)b * SLAB;

    // (a) pure read burst: 16 rows x 32KB, fully sequential
    float m0=3e38f,m1=3e38f,m2=3e38f,m3=3e38f,
          m4=3e38f,m5=3e38f,m6=3e38f,m7=3e38f;
    for (int r = 0; r < SLAB; ++r) {
        const long rb = (row0 + r) * COLS;
        float4 v = *reinterpret_cast<const float4*>(x + rb + t * 4);
        m0 = fminf(m0, v.x); m1 = fminf(m1, v.y);
        m2 = fminf(m2, v.z); m3 = fminf(m3, v.w);
        v = *reinterpret_cast<const float4*>(x + rb + 4096 + t * 4);
        m4 = fminf(m4, v.x); m5 = fminf(m5, v.y);
        m6 = fminf(m6, v.z); m7 = fminf(m7, v.w);
    }
    *reinterpret_cast<float4*>(pminx + (long)b * COLS + t * 4) =
        make_float4(m0, m1, m2, m3);
    *reinterpret_cast<float4*>(pminx + (long)b * COLS + 4096 + t * 4) =
        make_float4(m4, m5, m6, m7);

    // (b) pure write burst: zero this slab's 512KB region of out
    const float4 z = make_float4(0.f, 0.f, 0.f, 0.f);
    float4* o4 = reinterpret_cast<float4*>(out + row0 * COLS);
#pragma unroll 4
    for (int i = t; i < SLAB * COLS / 4; i += 1024) o4[i] = z;
}

// -------- K2: per-column wave — prune slabs, gather, Michelot, scatter ------
__global__ __launch_bounds__(256, 4)
void k_solve(const float* __restrict__ x, const float* __restrict__ a,
             const float* __restrict__ pminx, float* __restrict__ out)
{
    __shared__ float scand[4][CAPW];
    __shared__ int   srow[4][CAPW];

    const int t    = threadIdx.x;
    const int lane = t & 63;
    const int w    = t >> 6;
    const int col  = blockIdx.x * 4 + w;
    const float s  = -expf(a[0]);           // s < 0 always

    // (1) scan 256 slab minima -> colmin
    float sm[4];
#pragma unroll
    for (int i = 0; i < 4; ++i)
        sm[i] = pminx[(long)(lane + 64 * i) * COLS + col];
    float mn = fminf(fminf(sm[0], sm[1]), fminf(sm[2], sm[3]));
#pragma unroll
    for (int m = 1; m < 64; m <<= 1) mn = fminf(mn, __shfl_xor(mn, m, 64));
    // x < thr  <=>  z > colmax_z - 1 (with 2e-6 relative margin)
    const float thr = mn - 1.000002f / s;

    // (2) ballot-walk qualifying slabs, compact candidates into LDS
    int K = 0;
#pragma unroll
    for (int i = 0; i < 4; ++i) {
        unsigned long long bm = __ballot(sm[i] < thr);
        while (bm) {
            const int bit  = __ffsll((long long)bm) - 1;
            bm &= bm - 1;
            const int slab = 64 * i + bit;
            const int row  = slab * SLAB + lane;
            float xv = 0.f; bool c = false;
            if (lane < SLAB) {
                xv = x[(long)row * COLS + col];
                c  = xv < thr;
            }
            const unsigned long long cb = __ballot(c);
            const int pos = K + __popcll(cb & ((1ull << lane) - 1ull));
            if (c && pos < CAPW) { scand[w][pos] = s * xv; srow[w][pos] = row; }
            K += __popcll(cb);
        }
    }

    // (3) exact Michelot + scatter
    if (K <= CAPW) {
        float v = -3.3e38f; int row = 0;
        if (lane < K) { v = scand[w][lane]; row = srow[w][lane]; }
        float tau = -3.0e38f, prev = 0.f;
        for (int it = 0; it < CAPW + 4; ++it) {
            const bool act = v > tau;
            float ss = act ? v : 0.f;
            float sc = act ? 1.f : 0.f;
#pragma unroll
            for (int m = 1; m < 64; m <<= 1) {
                ss += __shfl_xor(ss, m, 64);
                sc += __shfl_xor(sc, m, 64);
            }
            tau = (ss - 1.0f) / sc;          // sc >= 1 (col min is a candidate)
            if (sc == prev) break;
            prev = sc;
        }
        if (v > tau) out[(long)row * COLS + col] = v - tau;   // out zeroed by K1
    } else {
        // overflow fallback: exact Michelot over the full column + scatter
        float tau = -3.0e38f, prev = 0.f;
        for (int it = 0; it < 256; ++it) {
            float ss = 0.f, sc = 0.f;
            for (int i = 0; i < ROWS / 64; ++i) {
                const float zz = s * x[(long)(lane + i * 64) * COLS + col];
                if (zz > tau) { ss += zz; sc += 1.f; }
            }
#pragma unroll
            for (int m = 1; m < 64; m <<= 1) {
                ss += __shfl_xor(ss, m, 64);
                sc += __shfl_xor(sc, m, 64);
            }
            tau = (ss - 1.0f) / sc;
            if (sc == prev) break;
            prev = sc;
        }
        for (int i = 0; i < ROWS / 64; ++i) {
            const long r = lane + i * 64;
            const float zz = s * x[r * COLS + col];
            if (zz > tau) out[r * COLS + col] = zz - tau;
        }
    }
}

extern "C" void kernel_launch(void* const* d_in, const int* in_sizes, int n_in,
                              void* d_out, int out_size, void* d_ws, size_t ws_size,
                              hipStream_t stream) {
    const float* x = (const float*)d_in[0];
    const float* a = (const float*)d_in[1];
    float* out = (float*)d_out;

    float* pminx = (float*)d_ws;                     // 8 MiB

    hipLaunchKernelGGL(k_pmax_zero, dim3(NSLAB), dim3(1024), 0, stream,
                       x, pminx, out);
    hipLaunchKernelGGL(k_solve, dim3(COLS / 4), dim3(256), 0, stream,
                       x, a, pminx, out);
}

// Round 14
// 261.193 us; speedup vs baseline: 1.0483x; 1.0483x over previous
//
#include <hip/hip_runtime.h>
#include <math.h>

// Sparsemax along axis 0 of z = -exp(a)*x, x: (4096, 8192) f32 row-major.
//
// R14 (resubmit after container infra failure): copy-shaped k_pmax (flat
// grid-stride), R12 skeleton otherwise.
// R13 measurement: block-tiled readers cap at ~2.5-3.2 TB/s (k_pmax_zero:
// 270MB in 84us) while the runtime's flat grid-stride fill hits 6.5 TB/s.
// Every block-tiled reader variant (R4/R7/R8/R13) landed 1.1-3.2 TB/s, so
// the last untested variable is KERNEL SHAPE. This k_pmax is shaped exactly
// like a fill/copy: 2048 blocks x 256 thr, 16 grid-stride float4 loads per
// thread, whole-grid front sweeps x contiguously. The reduction survives
// because stride = 2048*256 float4 = exactly 64 rows: thread q's samples
// all live in float4-column (q % 2048), rows {q/2048 + 256k}, so fmin4
// registers are valid per-column partials -> pmin[q/2048][col] (coalesced
// 4KB/block, same 256x8192 layout as R12; only the row reconstruction in
// k_solve changes: rows of partial rb are rb + 256*lane).
//
// Pipeline (3 dispatches):
//   memset(out): pure 128 MiB write stream (engine rate).
//   k_pmax: flat grid-stride col-min partials (THE mandatory HBM read).
//   k_solve: one wave/col (R12-proven): reduce 256 partials -> thr =
//       colmin + (1+eps)/|s| (x-units; z > colmax_z-1 <=> x < thr, s<0;
//       eps keeps candidates a strict SUPERSET of support under rounding);
//       ballot-walk flagged partials (~2-3/col), gather 16 rows each at
//       256-row stride (L2/L3-hot), ballot-prefix compact into LDS; exact
//       Michelot on <=64 candidates; scatter ~5 nonzeros. K>64 -> exact
//       full-column fallback (correctness never statistical).
//
// ws: [0, 8M) pmin f32[256][8192].

constexpr int ROWS  = 4096;
constexpr int COLS  = 8192;
constexpr int NPART = 256;           // partials per column
constexpr int GSTRD = 2048 * 256;    // grid-stride in float4 (= 64 rows)
constexpr int GITER = (ROWS * COLS / 4) / GSTRD;   // 16
constexpr int CAPW  = 64;            // candidate capacity per column (1/lane)

// ---------- K1: copy-shaped grid-stride col-min partials ----------
__global__ __launch_bounds__(256)
void k_pmax(const float* __restrict__ x, float* __restrict__ pmin)
{
    const int q    = blockIdx.x * 256 + threadIdx.x;   // [0, 524288)
    const int rb   = q >> 11;                          // partial index [0,256)
    const float4* x4 = reinterpret_cast<const float4*>(x);

    float m0 = 3e38f, m1 = 3e38f, m2 = 3e38f, m3 = 3e38f;
#pragma unroll
    for (int k = 0; k < GITER; ++k) {
        const float4 v = x4[(long)k * GSTRD + q];
        m0 = fminf(m0, v.x); m1 = fminf(m1, v.y);
        m2 = fminf(m2, v.z); m3 = fminf(m3, v.w);
    }
    // pmin[rb][col]: block writes a contiguous 4KB run (col4 = q % 2048)
    *reinterpret_cast<float4*>(pmin + (long)rb * COLS + (q & 2047) * 4) =
        make_float4(m0, m1, m2, m3);
}

// -------- K2: per-column wave — prune groups, gather, Michelot, scatter ------
__global__ __launch_bounds__(256, 4)
void k_solve(const float* __restrict__ x, const float* __restrict__ a,
             const float* __restrict__ pmin, float* __restrict__ out)
{
    __shared__ float scand[4][CAPW];
    __shared__ int   srow[4][CAPW];

    const int t    = threadIdx.x;
    const int lane = t & 63;
    const int w    = t >> 6;
    const int col  = blockIdx.x * 4 + w;
    const float s  = -expf(a[0]);           // s < 0 always

    // (1) scan 256 partial minima -> colmin
    float sm[4];
#pragma unroll
    for (int i = 0; i < 4; ++i)
        sm[i] = pmin[(long)(lane + 64 * i) * COLS + col];
    float mn = fminf(fminf(sm[0], sm[1]), fminf(sm[2], sm[3]));
#pragma unroll
    for (int m = 1; m < 64; m <<= 1) mn = fminf(mn, __shfl_xor(mn, m, 64));
    // x < thr  <=>  z > colmax_z - 1 (with 2e-6 relative margin)
    const float thr = mn - 1.000002f / s;

    // (2) ballot-walk qualifying partials; partial rb covers rows rb + 256k
    int K = 0;
#pragma unroll
    for (int i = 0; i < 4; ++i) {
        unsigned long long bm = __ballot(sm[i] < thr);
        while (bm) {
            const int bit = __ffsll((long long)bm) - 1;
            bm &= bm - 1;
            const int rb  = 64 * i + bit;
            const int row = rb + 256 * lane;           // lane < 16 valid
            float xv = 0.f; bool c = false;
            if (lane < 16) {
                xv = x[(long)row * COLS + col];
                c  = xv < thr;
            }
            const unsigned long long cb = __ballot(c);
            const int pos = K + __popcll(cb & ((1ull << lane) - 1ull));
            if (c && pos < CAPW) { scand[w][pos] = s * xv; srow[w][pos] = row; }
            K += __popcll(cb);
        }
    }

    // (3) exact Michelot + scatter
    if (K <= CAPW) {
        float v = -3.3e38f; int row = 0;
        if (lane < K) { v = scand[w][lane]; row = srow[w][lane]; }
        float tau = -3.0e38f, prev = 0.f;
        for (int it = 0; it < CAPW + 4; ++it) {
            const bool act = v > tau;
            float ss = act ? v : 0.f;
            float sc = act ? 1.f : 0.f;
#pragma unroll
            for (int m = 1; m < 64; m <<= 1) {
                ss += __shfl_xor(ss, m, 64);
                sc += __shfl_xor(sc, m, 64);
            }
            tau = (ss - 1.0f) / sc;          // sc >= 1 (col min is a candidate)
            if (sc == prev) break;
            prev = sc;
        }
        if (v > tau) out[(long)row * COLS + col] = v - tau;   // out pre-zeroed
    } else {
        // overflow fallback: exact Michelot over the full column + scatter
        float tau = -3.0e38f, prev = 0.f;
        for (int it = 0; it < 256; ++it) {
            float ss = 0.f, sc = 0.f;
            for (int i = 0; i < ROWS / 64; ++i) {
                const float zz = s * x[(long)(lane + i * 64) * COLS + col];
                if (zz > tau) { ss += zz; sc += 1.f; }
            }
#pragma unroll
            for (int m = 1; m < 64; m <<= 1) {
                ss += __shfl_xor(ss, m, 64);
                sc += __shfl_xor(sc, m, 64);
            }
            tau = (ss - 1.0f) / sc;
            if (sc == prev) break;
            prev = sc;
        }
        for (int i = 0; i < ROWS / 64; ++i) {
            const long r = lane + i * 64;
            const float zz = s * x[r * COLS + col];
            if (zz > tau) out[r * COLS + col] = zz - tau;
        }
    }
}

extern "C" void kernel_launch(void* const* d_in, const int* in_sizes, int n_in,
                              void* d_out, int out_size, void* d_ws, size_t ws_size,
                              hipStream_t stream) {
    const float* x = (const float*)d_in[0];
    const float* a = (const float*)d_in[1];
    float* out = (float*)d_out;

    float* pmin = (float*)d_ws;                      // 8 MiB

    // pure-write stream (R10 lesson: keep directions separate)
    hipMemsetAsync(out, 0, (size_t)ROWS * COLS * sizeof(float), stream);
    hipLaunchKernelGGL(k_pmax, dim3(GSTRD / 256), dim3(256), 0, stream, x, pmin);
    hipLaunchKernelGGL(k_solve, dim3(COLS / 4), dim3(256), 0, stream,
                       x, a, pmin, out);
}